// Round 7
// baseline (7341.505 us; speedup 1.0000x reference)
//
#include <hip/hip_runtime.h>
#include <math.h>

constexpr int kB = 256;
constexpr int kT = 200;
constexpr int kD = 512;
constexpr int kU = 1024;
constexpr int kG = 4096;   // 4*U

typedef short frag8 __attribute__((ext_vector_type(8)));     // 8 bf16 (4 VGPRs)
typedef float floatx4 __attribute__((ext_vector_type(4)));   // MFMA C/D frag
typedef unsigned short ushort_t;

__device__ __forceinline__ ushort_t f2bf(float f) {
    union { float f; unsigned int u; } v; v.f = f;
    unsigned int r = v.u + 0x7fffu + ((v.u >> 16) & 1u);   // RNE
    return (ushort_t)(r >> 16);
}
__device__ __forceinline__ float bf2f(ushort_t h) {
    union { unsigned int u; float f; } v; v.u = ((unsigned int)h) << 16;
    return v.f;
}

// ---------------------------------------------------------------------------
// Repack [W (K1 rows); Uw (K-K1 rows)] fp32 [*,4096] -> bf16 fragment order.
// Gate-interleaved columns: n_new = 4*j + g  <->  n_old = g*1024 + j.
// frag8 addr (units): ((nb*nkb + kb)*4 + ct)*64 + lane  (verified, absmax 0.0)
// ---------------------------------------------------------------------------
__global__ __launch_bounds__(256)
void repack_weights(const float* __restrict__ W, const float* __restrict__ Uw,
                    int K1, int K, ushort_t* __restrict__ out)
{
    const int nkb = K >> 5;
    const int kb = blockIdx.x % nkb;
    const int nb = blockIdx.x / nkb;
    __shared__ ushort_t tile[2048];
    const int tid = threadIdx.x;
#pragma unroll
    for (int i = 0; i < 8; i++) {
        int idx  = tid + (i << 8);         // 0..2047
        int kl   = idx >> 6;               // 0..31
        int lcol = idx & 63;               // 0..63
        int g  = lcol >> 4;
        int jl = lcol & 15;
        int k  = (kb << 5) + kl;
        int n_old = (g << 10) + (nb << 4) + jl;
        float v = (k < K1) ? W[(long)k * kG + n_old]
                           : Uw[(long)(k - K1) * kG + n_old];
        int n_new_l = (jl << 2) + g;       // local packed column
        int ng = n_new_l >> 4, nl = n_new_l & 15;
        int quad = kl >> 3, e = kl & 7;
        tile[ng * 512 + (quad * 16 + nl) * 8 + e] = f2bf(v);
    }
    __syncthreads();
    long base = ((long)(nb * nkb + kb)) * 2048;
    *(frag8*)&out[base + tid * 8] = *(frag8*)&tile[tid * 8];
}

__global__ __launch_bounds__(256)
void repack_bias(const float* __restrict__ b1, const float* __restrict__ b2,
                 float* __restrict__ o1, float* __restrict__ o2)
{
    int n = blockIdx.x * blockDim.x + threadIdx.x;   // 0..4095
    int n_old = ((n & 3) << 10) + (n >> 2);
    o1[n] = b1[n_old];
    o2[n] = b2[n_old];
}

// One-time embedding gather + fp32->bf16: xbf[b*T+t][d].
__global__ __launch_bounds__(128)
void xgather(const int* __restrict__ tokens, const float* __restrict__ emb,
             ushort_t* __restrict__ xbf)
{
    int bt = blockIdx.x;
    int tok = tokens[bt];
    float4 v = *(const float4*)(emb + (long)tok * kD + threadIdx.x * 4);
    unsigned int lo = ((unsigned int)f2bf(v.y) << 16) | f2bf(v.x);
    unsigned int hi = ((unsigned int)f2bf(v.w) << 16) | f2bf(v.z);
    uint2 p; p.x = lo; p.y = hi;
    *(uint2*)(xbf + (long)bt * kD + threadIdx.x * 4) = p;
}

// ===========================================================================
// PERSISTENT PATH (fence-free, write-once h sequences).
// 256 blocks x 512 thr (1 block/CU, pinned by ~146 KB LDS). Blocks 0..127 =
// layer2, 128..255 = layer1. Each block owns 32 packed gate-cols (8 h units),
// stages its weight slice into LDS ONCE -> zero weight traffic per step.
// NO acquire fences, NO bypass loads, NO grid barrier: h1/h2 are full
// 201-slot write-once sequences, so no L1/L2 line can ever be stale and all
// A-reads are plain cached loads (L2-broadcast within each XCD). Writers
// flush via RELEASE fetch_add (buffer_wbl2); readers poll relaxed flags.
// Layer1 free-runs ahead of layer2 (its own flag chain is the only bound).
// c-state lives in registers for all 200 steps.
// step_block = round-2 verified core (absmax 0.0), bypass->plain loads only.
// ===========================================================================
struct Batch { frag8 A[8]; frag8 B[8]; };

template<int K1KB>
__device__ __forceinline__ void load_batch(int bi, Batch& bb,
    const ushort_t* const (&a1p)[2], const ushort_t* const (&a2p)[2],
    const frag8* __restrict__ wl)
{
    const int kb0 = bi * 4;
#pragma unroll
    for (int u = 0; u < 4; u++) {
        bb.B[u*2+0] = wl[((kb0+u)*2+0) * 64];
        bb.B[u*2+1] = wl[((kb0+u)*2+1) * 64];
    }
    if (kb0 < K1KB) {      // batches are 4-kb aligned; K1KB % 4 == 0
#pragma unroll
        for (int u = 0; u < 4; u++)
#pragma unroll
            for (int i = 0; i < 2; i++)
                bb.A[u*2+i] = *(const frag8*)(a1p[i] + (kb0+u) * 32);
    } else {
#pragma unroll
        for (int u = 0; u < 4; u++)
#pragma unroll
            for (int i = 0; i < 2; i++)
                bb.A[u*2+i] = *(const frag8*)(a2p[i] + (kb0+u-K1KB) * 32);
    }
}

__device__ __forceinline__ void mfma_batch(const Batch& bb, floatx4 (&acc)[2][2])
{
#pragma unroll
    for (int u = 0; u < 4; u++)
#pragma unroll
        for (int mi = 0; mi < 2; mi++)
#pragma unroll
            for (int ct = 0; ct < 2; ct++)
                acc[mi][ct] = __builtin_amdgcn_mfma_f32_16x16x32_bf16(
                    bb.A[u*2+mi], bb.B[u*2+ct], acc[mi][ct], 0, 0, 0);
}

__device__ __forceinline__ void wait_flag(const int* f, int need) {
    if (need <= 0) return;
    while (__hip_atomic_load(f, __ATOMIC_RELAXED, __HIP_MEMORY_SCOPE_AGENT) < need)
        __builtin_amdgcn_s_sleep(4);
}

__device__ __forceinline__ void arrive(int* cnt, int* flag, int stepdone) {
    // RELEASE fetch_add: buffer_wbl2 flushes this XCD's dirty h lines to L3
    int old = __hip_atomic_fetch_add(cnt, 1, __ATOMIC_RELEASE, __HIP_MEMORY_SCOPE_AGENT);
    if (old == 128 * stepdone - 1)
        __hip_atomic_store(flag, stepdone, __ATOMIC_RELEASE, __HIP_MEMORY_SCOPE_AGENT);
}

template<int NKB, int K1KB>
__device__ __forceinline__ void step_block(
    const ushort_t* __restrict__ A1, long a1_rs, long a1_off,
    const ushort_t* __restrict__ A2,              // row stride kU
    const ushort_t* __restrict__ wlds_,
    float4 bias4, float (&creg)[2][2],
    ushort_t* __restrict__ hOut, int ub, float* __restrict__ zsw)
{
    const int tid = threadIdx.x, lane = tid & 63, wave = tid >> 6;
    const int wrow = wave << 5;                    // wave owns 32 rows
    const int r0 = wrow + (lane & 15);
    const int kq = (lane >> 4) << 3;

    const ushort_t* a1p[2]; const ushort_t* a2p[2];
#pragma unroll
    for (int i = 0; i < 2; i++) {
        a1p[i] = A1 + (long)(r0 + 16*i) * a1_rs + a1_off + kq;
        a2p[i] = A2 + (long)(r0 + 16*i) * kU + kq;
    }
    const frag8* wl = (const frag8*)wlds_ + lane;

    floatx4 acc[2][2];
#pragma unroll
    for (int i = 0; i < 2; i++) {
        acc[i][0] = (floatx4){0.f,0.f,0.f,0.f};
        acc[i][1] = (floatx4){0.f,0.f,0.f,0.f};
    }

    constexpr int NBATCH = NKB / 4;                // 16 (L2) or 12 (L1) — even
    Batch X, Y;
    load_batch<K1KB>(0, X, a1p, a2p, wl);
#pragma unroll 1
    for (int bi = 0; bi < NBATCH; bi += 2) {
        load_batch<K1KB>(bi + 1, Y, a1p, a2p, wl);
        mfma_batch(X, acc);
        if (bi + 2 < NBATCH) load_batch<K1KB>(bi + 2, X, a1p, a2p, wl);
        mfma_batch(Y, acc);
    }

    // Epilogue: per-wave LDS transpose (intra-wave DS FIFO ordering), fp32 gates.
    const int q = lane >> 4, c16 = lane & 15;
    const int rl0 = lane >> 3, jl = lane & 7;      // jl constant per lane
#pragma unroll
    for (int mi = 0; mi < 2; mi++) {
#pragma unroll
        for (int ct = 0; ct < 2; ct++)
#pragma unroll
            for (int r = 0; r < 4; r++)
                zsw[((q << 2) + r) * 36 + (ct << 4) + c16] = acc[mi][ct][r];
#pragma unroll
        for (int ii = 0; ii < 2; ii++) {
            int rowl = rl0 + (ii << 3);
            float4 z4 = *(float4*)&zsw[rowl * 36 + (jl << 2)];
            float zi = z4.x + bias4.x, zf = z4.y + bias4.y;
            float zg = z4.z + bias4.z, zo = z4.w + bias4.w;
            float ig = 1.f / (1.f + __expf(-zi));
            float fg = 1.f / (1.f + __expf(-zf));
            float og = 1.f / (1.f + __expf(-zo));
            float gg = 1.f - 2.f / (__expf(2.f * zg) + 1.f);   // tanh
            float cn = fg * creg[mi][ii] + ig * gg;
            creg[mi][ii] = cn;
            float tc = 1.f - 2.f / (__expf(2.f * cn) + 1.f);   // tanh
            int m = wrow + (mi << 4) + rowl;
            hOut[(long)m * kU + ub + jl] = f2bf(og * tc);
        }
    }
}

// Slot convention: h1seq slot s holds h1[s-1] (slot 0 = zeros); h2seq slot s
// holds h2[s-1]. Layer2 superstep l (1..200): reads h1 slot l + h2 slot l-1,
// writes h2 slot l. Layer1 step t (0..199): reads h1 slot t, writes slot t+1.
__global__ __launch_bounds__(512, 1)
void lstm_persist(const ushort_t* __restrict__ W1p, const ushort_t* __restrict__ W2p,
                  const float* __restrict__ b1p, const float* __restrict__ b2p,
                  const ushort_t* __restrict__ xbf,
                  ushort_t* __restrict__ h1seq,   // 201 x [kB*kU], write-once
                  ushort_t* __restrict__ h2seq,   // 201 x [kB*kU], write-once
                  int* __restrict__ sync)         // [0]=cnt1 [32]=flag1 [64]=cnt2 [96]=flag2
{
    __shared__ __align__(16) ushort_t wlds[65536];   // 128 KB weight slice
    __shared__ __align__(16) float zs[8][576];       // 18 KB epilogue transpose

    const int bid = blockIdx.x;
    const bool isL2 = bid < 128;
    const int b = isL2 ? bid : bid - 128;            // owns packed cols [32b, 32b+32)
    const int tid = threadIdx.x, lane = tid & 63, wave = tid >> 6;

    // ---- one-time: stage weight slice into LDS ----
    {
        const frag8* wg = (const frag8*)(isL2 ? W2p : W1p);
        const int NKB = isL2 ? 64 : 48;
        const int nb2 = b >> 1, cbase = (b & 1) * 2;
        const long gb = (long)nb2 * NKB * 256;       // frag8 units
        frag8* wl = (frag8*)wlds;
        for (int i = tid; i < NKB * 128; i += 512) {
            int kb = i >> 7, r = i & 127;
            wl[i] = wg[gb + ((long)kb * 4 + cbase + (r >> 6)) * 64 + (r & 63)];
        }
    }

    const float4* biasP4 = (const float4*)(isL2 ? b2p : b1p);
    const float4 bias4 = biasP4[b * 8 + (lane & 7)]; // this lane's 4 gate biases

    float creg[2][2];                                // c-state: 4 fp32/lane, whole seq
    creg[0][0] = creg[0][1] = creg[1][0] = creg[1][1] = 0.f;

    float* zsw = zs[wave];
    const int ub = b << 3;                           // h-unit column base
    int* cnt1  = sync;      int* flag1 = sync + 32;
    int* cnt2  = sync + 64; int* flag2 = sync + 96;
    const size_t SZ = (size_t)kB * kU;

    __syncthreads();                                 // weights staged

    if (isL2) {
#pragma unroll 1
        for (int l = 1; l <= kT; l++) {
            if (tid == 0) { wait_flag(flag1, l); wait_flag(flag2, l - 1); }
            __syncthreads();                         // ordering point for all waves
            step_block<64, 32>(h1seq + (size_t)l * SZ, kU, 0,
                               h2seq + (size_t)(l - 1) * SZ, wlds,
                               bias4, creg,
                               h2seq + (size_t)l * SZ, ub, zsw);
            __syncthreads();                         // drains vmcnt: stores issued
            if (tid == 0) arrive(cnt2, flag2, l);
        }
    } else {
#pragma unroll 1
        for (int t = 0; t < kT; t++) {
            if (tid == 0) wait_flag(flag1, t);
            __syncthreads();
            step_block<48, 16>(xbf, (long)kT * kD, (long)t * kD,
                               h1seq + (size_t)t * SZ, wlds,
                               bias4, creg,
                               h1seq + (size_t)(t + 1) * SZ, ub, zsw);
            __syncthreads();
            if (tid == 0) arrive(cnt1, flag1, t + 1);
        }
    }
}

// ===========================================================================
// FALLBACK PATH (round-0 verified multi-launch, ~5.87 ms) — used if the
// workspace is too small for the write-once h sequences.
// ===========================================================================
struct BatchF { frag8 A[8]; frag8 B[16]; };

template<int K1BK>
__device__ __forceinline__ void load_batchF(int b, BatchF& bb,
    const ushort_t* a1p0, const ushort_t* a1p1,
    const ushort_t* a2p0, const ushort_t* a2p1,
    const frag8* wbase)
{
    const int kb0 = b * 4;
    if (kb0 < K1BK) {
#pragma unroll
        for (int u = 0; u < 4; u++) {
            const frag8* wp = wbase + (kb0 + u) * 256;
            bb.B[u*4+0] = wp[0];   bb.B[u*4+1] = wp[64];
            bb.B[u*4+2] = wp[128]; bb.B[u*4+3] = wp[192];
            bb.A[u*2+0] = *(const frag8*)(a1p0 + (kb0 + u) * 32);
            bb.A[u*2+1] = *(const frag8*)(a1p1 + (kb0 + u) * 32);
        }
    } else {
#pragma unroll
        for (int u = 0; u < 4; u++) {
            const frag8* wp = wbase + (kb0 + u) * 256;
            bb.B[u*4+0] = wp[0];   bb.B[u*4+1] = wp[64];
            bb.B[u*4+2] = wp[128]; bb.B[u*4+3] = wp[192];
            bb.A[u*2+0] = *(const frag8*)(a2p0 + (kb0 - K1BK + u) * 32);
            bb.A[u*2+1] = *(const frag8*)(a2p1 + (kb0 - K1BK + u) * 32);
        }
    }
}

__device__ __forceinline__ void mfma_batchF(const BatchF& bb, floatx4 acc[2][4])
{
#pragma unroll
    for (int u = 0; u < 4; u++)
#pragma unroll
        for (int mi = 0; mi < 2; mi++)
#pragma unroll
            for (int ct = 0; ct < 4; ct++)
                acc[mi][ct] = __builtin_amdgcn_mfma_f32_16x16x32_bf16(
                    bb.A[u*2+mi], bb.B[u*4+ct], acc[mi][ct], 0, 0, 0);
}

template<int NKB, int K1BK>
__device__ __forceinline__ void step_coreF(
    const ushort_t* __restrict__ A1, long a1_rs, long a1_off,
    const ushort_t* __restrict__ A2,
    const ushort_t* __restrict__ Wp,
    const float4* __restrict__ biasP4,
    float* __restrict__ cSt, ushort_t* __restrict__ hOut,
    float* __restrict__ zsw)
{
    const int tid  = threadIdx.x;
    const int lane = tid & 63;
    const int wave = tid >> 6;
    const int nb2  = blockIdx.x * 2 + (wave & 1);        // 64-col superblock 0..63
    const int wrow = (blockIdx.y << 6) + ((wave >> 1) << 5);
    const int kq   = (lane >> 4) << 3;

    const int r0 = wrow + (lane & 15);
    const ushort_t* a1p0 = A1 + (long)r0 * a1_rs + a1_off + kq;
    const ushort_t* a1p1 = A1 + (long)(r0 + 16) * a1_rs + a1_off + kq;
    const ushort_t* a2p0 = A2 + (long)r0 * kU + kq;
    const ushort_t* a2p1 = A2 + (long)(r0 + 16) * kU + kq;
    const frag8* wbase = (const frag8*)Wp + (long)nb2 * (NKB * 256) + lane;

    floatx4 acc[2][4];
#pragma unroll
    for (int i = 0; i < 2; i++)
#pragma unroll
        for (int j = 0; j < 4; j++) acc[i][j] = (floatx4){0.f, 0.f, 0.f, 0.f};

    constexpr int NBATCH = NKB / 4;
    BatchF X, Y;
    load_batchF<K1BK>(0, X, a1p0, a1p1, a2p0, a2p1, wbase);
#pragma unroll 1
    for (int b = 0; b < NBATCH; b += 2) {
        load_batchF<K1BK>(b + 1, Y, a1p0, a1p1, a2p0, a2p1, wbase);
        mfma_batchF(X, acc);
        if (b + 2 < NBATCH)
            load_batchF<K1BK>(b + 2, X, a1p0, a1p1, a2p0, a2p1, wbase);
        mfma_batchF(Y, acc);
    }

    const int q = lane >> 4, c16 = lane & 15;
#pragma unroll 1
    for (int mi = 0; mi < 2; mi++) {
#pragma unroll
        for (int ct = 0; ct < 4; ct++)
#pragma unroll
            for (int r = 0; r < 4; r++)
                zsw[((q << 2) + r) * 68 + (ct << 4) + c16] = acc[mi][ct][r];
#pragma unroll
        for (int ii = 0; ii < 4; ii++) {
            int cell = lane + (ii << 6);
            int rowl = cell >> 4, jl = cell & 15;
            float4 z4 = *(float4*)&zsw[rowl * 68 + (jl << 2)];
            float4 bv = biasP4[(nb2 << 4) + jl];
            float zi = z4.x + bv.x, zf = z4.y + bv.y;
            float zg = z4.z + bv.z, zo = z4.w + bv.w;
            float ig = 1.f / (1.f + __expf(-zi));
            float fg = 1.f / (1.f + __expf(-zf));
            float og = 1.f / (1.f + __expf(-zo));
            float gg = 1.f - 2.f / (__expf(2.f * zg) + 1.f);   // tanh
            int m = wrow + (mi << 4) + rowl;
            long ci = (long)m * kU + (nb2 << 4) + jl;
            float cn = fg * cSt[ci] + ig * gg;
            float tc = 1.f - 2.f / (__expf(2.f * cn) + 1.f);   // tanh
            cSt[ci] = cn;
            hOut[ci] = f2bf(og * tc);
        }
    }
}

__global__ __launch_bounds__(256, 1)
void lstm_mergedF(int zmask,
    const ushort_t* h1_for2, const ushort_t* h2prev, const ushort_t* W2p,
    const float* b2p, float* c2, ushort_t* h2out,
    const ushort_t* xbf, int t1,
    const ushort_t* h1prev, const ushort_t* W1p,
    const float* b1p, float* c1, ushort_t* h1out)
{
    __shared__ __align__(16) float zs[4][16 * 68];
    float* zsw = zs[threadIdx.x >> 6];
    if (blockIdx.z == 0) {
        if (!(zmask & 1)) return;
        step_coreF<64, 32>(h1_for2, kU, 0, h2prev, W2p,
                           (const float4*)b2p, c2, h2out, zsw);
    } else {
        if (!(zmask & 2)) return;
        step_coreF<48, 16>(xbf, (long)kT * kD, (long)t1 * kD, h1prev, W1p,
                           (const float4*)b1p, c1, h1out, zsw);
    }
}

// out[b] = sigmoid(h[b,:] . Wfc + bfc), h in bf16
__global__ __launch_bounds__(256)
void fc_sigmoid(const ushort_t* __restrict__ h, const float* __restrict__ Wfc,
                const float* __restrict__ bfc, float* __restrict__ out)
{
    int b = blockIdx.x, tid = threadIdx.x;
    float s = 0.f;
    for (int j = tid; j < kU; j += 256) s += bf2f(h[(long)b * kU + j]) * Wfc[j];
    __shared__ float red[4];
    for (int off = 32; off > 0; off >>= 1) s += __shfl_down(s, off, 64);
    if ((tid & 63) == 0) red[tid >> 6] = s;
    __syncthreads();
    if (tid == 0) {
        float t = red[0] + red[1] + red[2] + red[3] + bfc[0];
        out[b] = 1.f / (1.f + expf(-t));
    }
}

extern "C" void kernel_launch(void* const* d_in, const int* in_sizes, int n_in,
                              void* d_out, int out_size, void* d_ws, size_t ws_size,
                              hipStream_t stream)
{
    (void)in_sizes; (void)n_in; (void)out_size;

    const int*   tokens = (const int*)d_in[0];
    const float* emb    = (const float*)d_in[1];
    const float* W1     = (const float*)d_in[2];
    const float* U1     = (const float*)d_in[3];
    const float* b1     = (const float*)d_in[4];
    const float* W2     = (const float*)d_in[5];
    const float* U2     = (const float*)d_in[6];
    const float* b2     = (const float*)d_in[7];
    const float* Wfc    = (const float*)d_in[8];
    const float* bfc    = (const float*)d_in[9];
    float* out = (float*)d_out;

    const size_t SZe = (size_t)kB * kU;                    // h slot elements

    // ---- persistent layout (~293 MB) ----
    ushort_t* W1p = (ushort_t*)d_ws;                       // [1536*4096] bf16
    ushort_t* W2p = W1p + (size_t)1536 * kG;               // [2048*4096] bf16
    float* b1p = (float*)(W2p + (size_t)2048 * kG);        // [4096] f32
    float* b2p = b1p + kG;                                 // [4096] f32
    int*   syncA = (int*)(b2p + kG);                       // 256 ints (1 KB)
    ushort_t* h1seq = (ushort_t*)(syncA + 256);            // 201 x [kB*kU] bf16
    ushort_t* h2seq = h1seq + 201 * SZe;                   // 201 x [kB*kU] bf16
    ushort_t* xbfP  = h2seq + 201 * SZe;                   // [B*T*512] bf16
    size_t need = (size_t)((char*)(xbfP + (size_t)kB * kT * kD) - (char*)d_ws);

    repack_weights<<<48 * 64, 256, 0, stream>>>(W1, U1, 512, 1536, W1p);
    repack_weights<<<64 * 64, 256, 0, stream>>>(W2, U2, 1024, 2048, W2p);
    repack_bias<<<16, 256, 0, stream>>>(b1, b2, b1p, b2p);

    if (ws_size >= need) {
        // ---------------- persistent fence-free path ----------------
        xgather<<<kB * kT, 128, 0, stream>>>(tokens, emb, xbfP);
        hipMemsetAsync(syncA, 0, 1024, stream);                    // flags
        hipMemsetAsync(h1seq, 0, SZe * sizeof(ushort_t), stream);  // h1[-1] = 0
        hipMemsetAsync(h2seq, 0, SZe * sizeof(ushort_t), stream);  // h2[-1] = 0

        void* args[] = { &W1p, &W2p, &b1p, &b2p, &xbfP, &h1seq, &h2seq, &syncA };
        hipLaunchCooperativeKernel((void*)lstm_persist, dim3(256), dim3(512),
                                   args, 0, stream);

        // final h2[199] lives in slot 200
        ushort_t* hfin = h2seq + 200 * SZe;
        fc_sigmoid<<<kB, 256, 0, stream>>>(hfin, Wfc, bfc, out);
    } else {
        // ---------------- round-0 multi-launch fallback (~86 MB) ----------------
        float* c1  = (float*)(b2p + kG);                   // [256*1024] f32
        float* c2  = c1 + SZe;
        ushort_t* hbuf = (ushort_t*)(c2 + SZe);            // 4 x [kB*kU] bf16
        ushort_t* h1b[2] = { hbuf, hbuf + SZe };
        ushort_t* h2b[2] = { hbuf + 2 * SZe, hbuf + 3 * SZe };
        ushort_t* xbf = hbuf + 4 * SZe;                    // [B*T*512] bf16

        xgather<<<kB * kT, 128, 0, stream>>>(tokens, emb, xbf);
        hipMemsetAsync(c1, 0, SZe * (2 * 4 + 4 * 2), stream);

        for (int l = 0; l <= kT; l++) {
            int t2 = l - 1, t1 = l;
            int zmask = (t2 >= 0 ? 1 : 0) | (t1 < kT ? 2 : 0);
            lstm_mergedF<<<dim3(32, 4, 2), 256, 0, stream>>>(zmask,
                h1b[(t2 + 1) & 1], h2b[t2 & 1], W2p, b2p, c2, h2b[(t2 + 1) & 1],
                xbf, t1, h1b[t1 & 1], W1p, b1p, c1, h1b[(t1 + 1) & 1]);
        }
        fc_sigmoid<<<kB, 256, 0, stream>>>(h2b[0], Wfc, bfc, out);
    }
}